// Round 8
// baseline (260.642 us; speedup 1.0000x reference)
//
#include <hip/hip_runtime.h>
#include <stdint.h>

#define DF 32
#define BN 256               // nodes per bucket (dst >> 8)
#define MAXB 512             // max buckets on fast path (nN <= 131072)
#define CHUNK 4096           // edges per partition WG
typedef unsigned long long u64;
typedef unsigned short u16;
typedef float f32x4 __attribute__((ext_vector_type(4)));
typedef unsigned short u16x4 __attribute__((ext_vector_type(4)));

static __device__ __forceinline__ u16 f2bf(float x) {     // RTN-even
    unsigned u = __float_as_uint(x);
    return (u16)((u + 0x7fff + ((u >> 16) & 1)) >> 16);
}
static __device__ __forceinline__ float bf2f(u16 b) {
    return __uint_as_float((unsigned)b << 16);
}

__global__ void k_zero(int* __restrict__ p, int n) {
    int i = blockIdx.x * blockDim.x + threadIdx.x;
    if (i < n) p[i] = 0;
}

// ======================= bucket partition prepass =======================

__global__ void k_bcount(const int* __restrict__ dst, int* __restrict__ bcnt,
                         int nE, int nbuck) {
    __shared__ int h[MAXB];
    for (int i = threadIdx.x; i < MAXB; i += blockDim.x) h[i] = 0;
    __syncthreads();
    for (int i = blockIdx.x * blockDim.x + threadIdx.x; i < nE;
         i += gridDim.x * blockDim.x)
        atomicAdd(&h[__builtin_nontemporal_load(dst + i) >> 8], 1);
    __syncthreads();
    for (int i = threadIdx.x; i < nbuck; i += blockDim.x)
        if (h[i]) atomicAdd(&bcnt[i], h[i]);
}

__global__ void k_bscan(const int* __restrict__ bcnt, int* __restrict__ bptr,
                        int* __restrict__ bcur, int nbuck) {
    __shared__ int a[MAXB], b[MAXB];
    int t = threadIdx.x;
    int v = (t < nbuck) ? bcnt[t] : 0;
    a[t] = v;
    __syncthreads();
    int* pin = a; int* pout = b;
    for (int off = 1; off < MAXB; off <<= 1) {
        pout[t] = pin[t] + ((t >= off) ? pin[t - off] : 0);
        __syncthreads();
        int* tmp = pin; pin = pout; pout = tmp;
    }
    int inc = pin[t];
    if (t < nbuck) { bptr[t] = inc - v; bcur[t] = inc - v; }
    if (t == nbuck - 1) bptr[nbuck] = inc;
}

// record = w(f32)<<32 | src<<8 | localDst  (needs nN < 2^24)
__global__ __launch_bounds__(512)
void k_bpart(const int* __restrict__ src, const int* __restrict__ dst,
             const float* __restrict__ w, int* __restrict__ bcur,
             u64* __restrict__ rec_g, int nE, int nbuck) {
    __shared__ u64 rec[CHUNK];
    __shared__ unsigned short rb[CHUNK];
    __shared__ int hist[MAXB], sa[MAXB], sb[MAXB], goff[MAXB], cur[MAXB];
    int t = threadIdx.x;
    int base = blockIdx.x * CHUNK;
    int cnt = min(CHUNK, nE - base);

    hist[t] = 0;
    __syncthreads();

    int myb[8]; u64 myrec[8];
#pragma unroll
    for (int j = 0; j < 8; j++) {
        int i = t + j * 512;
        if (i < cnt) {
            int d = __builtin_nontemporal_load(dst + base + i);
            myb[j] = d >> 8;
            myrec[j] = ((u64)__float_as_uint(__builtin_nontemporal_load(w + base + i)) << 32)
                     | ((u64)(unsigned)__builtin_nontemporal_load(src + base + i) << 8)
                     | (u64)(d & (BN - 1));
            atomicAdd(&hist[myb[j]], 1);
        } else myb[j] = -1;
    }
    __syncthreads();

    int v = hist[t];
    sa[t] = v;
    __syncthreads();
    int* pin = sa; int* pout = sb;
    for (int off = 1; off < MAXB; off <<= 1) {
        pout[t] = pin[t] + ((t >= off) ? pin[t - off] : 0);
        __syncthreads();
        int* tmp = pin; pin = pout; pout = tmp;
    }
    int excl = pin[t] - v;
    cur[t] = excl;
    int g = 0;
    if (t < nbuck && v > 0) g = atomicAdd(&bcur[t], v);
    goff[t] = g - excl;
    __syncthreads();

#pragma unroll
    for (int j = 0; j < 8; j++) {
        if (myb[j] >= 0) {
            int p = atomicAdd(&cur[myb[j]], 1);
            rec[p] = myrec[j];
            rb[p] = (unsigned short)myb[j];
        }
    }
    __syncthreads();

    for (int r = t; r < cnt; r += 512) {
        int bb = rb[r];
        __builtin_nontemporal_store(rec[r], rec_g + goff[bb] + r);
    }
}

// one WG per bucket: exact CSR from bucket-sorted rec_g.
// packed = w(f32)<<32 | src   (plain index, as R6)
__global__ __launch_bounds__(512)
void k_csr(const int* __restrict__ bptr, const u64* __restrict__ rec_g,
           int* __restrict__ rowptr, u64* __restrict__ packed, int nN, int nbuck) {
    __shared__ int cnt[BN], excl[BN];
    int b = blockIdx.x;
    int t = threadIdx.x;
    int s0 = bptr[b], s1 = bptr[b + 1];
    if (t < BN) cnt[t] = 0;
    __syncthreads();
    for (int i = s0 + t; i < s1; i += 512)
        atomicAdd(&cnt[(int)(rec_g[i] & (BN - 1))], 1);
    __syncthreads();
    if (t < BN) excl[t] = cnt[t];
    __syncthreads();
    for (int off = 1; off < BN; off <<= 1) {
        int u = 0;
        if (t < BN && t >= off) u = excl[t - off];
        __syncthreads();
        if (t < BN) excl[t] += u;
        __syncthreads();
    }
    int nodeBase = b * BN;
    if (t < BN) {
        int e = excl[t] - cnt[t];
        if (nodeBase + t < nN) rowptr[nodeBase + t] = s0 + e;
        cnt[t] = e;
    }
    if (b == nbuck - 1 && t == 0) rowptr[nN] = s1;
    __syncthreads();
    for (int i = s0 + t; i < s1; i += 512) {
        u64 r = rec_g[i];
        int ld = (int)(r & (BN - 1));
        int pos = s0 + atomicAdd(&cnt[ld], 1);
        __builtin_nontemporal_store((r & 0xffffffff00000000ull) | ((r >> 8) & 0xffffffull),
                                    packed + pos);
    }
}

// f32 -> bf16 cast (4 elems/thread)
__global__ void k_cast(const float* __restrict__ x, u16* __restrict__ y, int n4) {
    int i = blockIdx.x * blockDim.x + threadIdx.x;
    if (i >= n4) return;
    f32x4 v = __builtin_nontemporal_load(reinterpret_cast<const f32x4*>(x) + i);
    u16x4 o;
    o.x = f2bf(v.x); o.y = f2bf(v.y); o.z = f2bf(v.z); o.w = f2bf(v.w);
    __builtin_nontemporal_store(o, reinterpret_cast<u16x4*>(y) + i);
}

// ======================= pull SpMM (bf16 gathers, unroll-4 + masked tail) ====
// half-wave per node: lane f owns feature f. Streaming traffic (packed, emb,
// out, hn16) is non-temporal so h16 stays L2-resident. h16 gathers are cached.
// MODE: 0 first (out = emb+acc, hn=bf16(acc)), 1 mid (out+=acc, hn=bf16(acc)),
// 2 last (out = (out+acc)*0.25)
template <int MODE>
__global__ void k_pull(const int* __restrict__ rowptr, const u64* __restrict__ packed,
                       const u16* __restrict__ h16, u16* __restrict__ hn16,
                       const float* __restrict__ emb, float* __restrict__ out, int n) {
    int gid = blockIdx.x * blockDim.x + threadIdx.x;
    int node = gid >> 5;
    int f = gid & 31;
    if (node >= n) return;
    int s0 = rowptr[node], s1 = rowptr[node + 1];
    float acc0 = 0.f, acc1 = 0.f, acc2 = 0.f, acc3 = 0.f;
    int i = s0;
    for (; i + 4 <= s1; i += 4) {                 // 4 gathers in flight
        u64 p0 = __builtin_nontemporal_load(packed + i);
        u64 p1 = __builtin_nontemporal_load(packed + i + 1);
        u64 p2 = __builtin_nontemporal_load(packed + i + 2);
        u64 p3 = __builtin_nontemporal_load(packed + i + 3);
        float v0 = bf2f(h16[(size_t)(unsigned)(p0 & 0xffffffffu) * DF + f]);
        float v1 = bf2f(h16[(size_t)(unsigned)(p1 & 0xffffffffu) * DF + f]);
        float v2 = bf2f(h16[(size_t)(unsigned)(p2 & 0xffffffffu) * DF + f]);
        float v3 = bf2f(h16[(size_t)(unsigned)(p3 & 0xffffffffu) * DF + f]);
        acc0 += __uint_as_float((unsigned)(p0 >> 32)) * v0;
        acc1 += __uint_as_float((unsigned)(p1 >> 32)) * v1;
        acc2 += __uint_as_float((unsigned)(p2 >> 32)) * v2;
        acc3 += __uint_as_float((unsigned)(p3 >> 32)) * v3;
    }
    if (i < s1) {                                 // one masked batch for tail
        int lim = s1 - 1;
        u64 p0 = __builtin_nontemporal_load(packed + i);
        u64 p1 = __builtin_nontemporal_load(packed + (i + 1 < s1 ? i + 1 : lim));
        u64 p2 = __builtin_nontemporal_load(packed + (i + 2 < s1 ? i + 2 : lim));
        u64 p3 = __builtin_nontemporal_load(packed + (i + 3 < s1 ? i + 3 : lim));
        float v0 = bf2f(h16[(size_t)(unsigned)(p0 & 0xffffffffu) * DF + f]);
        float v1 = bf2f(h16[(size_t)(unsigned)(p1 & 0xffffffffu) * DF + f]);
        float v2 = bf2f(h16[(size_t)(unsigned)(p2 & 0xffffffffu) * DF + f]);
        float v3 = bf2f(h16[(size_t)(unsigned)(p3 & 0xffffffffu) * DF + f]);
        float w1 = (i + 1 < s1) ? __uint_as_float((unsigned)(p1 >> 32)) : 0.f;
        float w2 = (i + 2 < s1) ? __uint_as_float((unsigned)(p2 >> 32)) : 0.f;
        float w3 = (i + 3 < s1) ? __uint_as_float((unsigned)(p3 >> 32)) : 0.f;
        acc0 += __uint_as_float((unsigned)(p0 >> 32)) * v0;
        acc1 += w1 * v1;
        acc2 += w2 * v2;
        acc3 += w3 * v3;
    }
    float acc = (acc0 + acc1) + (acc2 + acc3);
    size_t o = (size_t)node * DF + f;
    if (MODE == 0) {
        __builtin_nontemporal_store(f2bf(acc), hn16 + o);
        float e = __builtin_nontemporal_load(emb + o);
        __builtin_nontemporal_store(e + acc, out + o);
    } else if (MODE == 1) {
        __builtin_nontemporal_store(f2bf(acc), hn16 + o);
        float ov = __builtin_nontemporal_load(out + o);
        __builtin_nontemporal_store(ov + acc, out + o);
    } else {
        float ov = __builtin_nontemporal_load(out + o);
        __builtin_nontemporal_store((ov + acc) * 0.25f, out + o);
    }
}

// ======================= fallback (R1 atomic path, f32) =======================

__global__ void spmm_scatter(const int* __restrict__ src, const int* __restrict__ dst,
                             const float* __restrict__ w, const float* __restrict__ h,
                             float* __restrict__ hn, int nE) {
    int i = blockIdx.x * blockDim.x + threadIdx.x;
    int total = nE * 8;
    if (i >= total) return;
    int e = i >> 3, g = i & 7;
    int s = src[e], t = dst[e];
    float wt = w[e];
    float4 v = reinterpret_cast<const float4*>(h)[(size_t)s * 8 + g];
    float* p = hn + (size_t)t * DF + g * 4;
    atomicAdd(p + 0, v.x * wt); atomicAdd(p + 1, v.y * wt);
    atomicAdd(p + 2, v.z * wt); atomicAdd(p + 3, v.w * wt);
}
__global__ void accum_first(const float* __restrict__ emb, const float* __restrict__ hn,
                            float* __restrict__ out, int n4) {
    int i = blockIdx.x * blockDim.x + threadIdx.x;
    if (i >= n4) return;
    float4 a = reinterpret_cast<const float4*>(emb)[i];
    float4 b = reinterpret_cast<const float4*>(hn)[i];
    reinterpret_cast<float4*>(out)[i] = make_float4(a.x+b.x, a.y+b.y, a.z+b.z, a.w+b.w);
}
__global__ void accum_mid(const float* __restrict__ hn, float* __restrict__ out, int n4) {
    int i = blockIdx.x * blockDim.x + threadIdx.x;
    if (i >= n4) return;
    float4 a = reinterpret_cast<float4*>(out)[i];
    float4 b = reinterpret_cast<const float4*>(hn)[i];
    reinterpret_cast<float4*>(out)[i] = make_float4(a.x+b.x, a.y+b.y, a.z+b.z, a.w+b.w);
}
__global__ void accum_last(const float* __restrict__ hn, float* __restrict__ out, int n4) {
    int i = blockIdx.x * blockDim.x + threadIdx.x;
    if (i >= n4) return;
    float4 a = reinterpret_cast<float4*>(out)[i];
    float4 b = reinterpret_cast<const float4*>(hn)[i];
    reinterpret_cast<float4*>(out)[i] = make_float4((a.x+b.x)*0.25f, (a.y+b.y)*0.25f,
                                                    (a.z+b.z)*0.25f, (a.w+b.w)*0.25f);
}

// ======================= launch =======================

extern "C" void kernel_launch(void* const* d_in, const int* in_sizes, int n_in,
                              void* d_out, int out_size, void* d_ws, size_t ws_size,
                              hipStream_t stream) {
    const float* emb = (const float*)d_in[0];
    const int*   src = (const int*)d_in[1];
    const int*   dst = (const int*)d_in[2];
    const float* w   = (const float*)d_in[3];
    float* out = (float*)d_out;

    const int nN = in_sizes[0] / DF;
    const int nE = in_sizes[1];
    const int nbuck = (nN + BN - 1) / BN;
    const size_t hbytes  = (size_t)nN * DF * sizeof(float);   // f32 matrix
    const size_t h16b    = (size_t)nN * DF * 2;               // bf16 matrix

    char* ws = (char*)d_ws;
    u16* E16 = (u16*)ws;
    u16* B16 = (u16*)(ws + h16b);
    u16* A16 = (u16*)(ws + 2 * h16b);
    u64* rec_g = (u64*)(ws + h16b);          // overlaps B16/A16; dead before pulls
    size_t recb = (((size_t)nE * 8 + 63) / 64) * 64;
    size_t off_pk = h16b + (recb > 2 * h16b ? recb : 2 * h16b);
    u64* packed = (u64*)(ws + off_pk);
    size_t roff = off_pk + recb;
    int* rowptr = (int*)(ws + roff);
    size_t boff = roff + (((size_t)(nN + 1) * 4 + 63) / 64) * 64;
    int* bcnt = (int*)(ws + boff);
    int* bptr = bcnt + MAXB;
    int* bcur = bptr + MAXB + 1;
    const size_t need = boff + (size_t)(3 * MAXB + 1) * 4;

    const dim3 blk(256);

    if (nbuck <= MAXB && nN < (1 << 24) && ws_size >= need) {
        const int n4 = nN * DF / 4;
        k_zero<<<(MAXB + 255) / 256, blk, 0, stream>>>(bcnt, MAXB);
        k_cast<<<(n4 + 255) / 256, blk, 0, stream>>>(emb, E16, n4);
        k_bcount<<<512, blk, 0, stream>>>(dst, bcnt, nE, nbuck);
        k_bscan<<<1, MAXB, 0, stream>>>(bcnt, bptr, bcur, nbuck);
        k_bpart<<<(nE + CHUNK - 1) / CHUNK, 512, 0, stream>>>(src, dst, w, bcur,
                                                              rec_g, nE, nbuck);
        k_csr<<<nbuck, 512, 0, stream>>>(bptr, rec_g, rowptr, packed, nN, nbuck);

        const int pgrid = (nN * 32 + 255) / 256;
        k_pull<0><<<pgrid, blk, 0, stream>>>(rowptr, packed, E16, B16, emb, out, nN);
        k_pull<1><<<pgrid, blk, 0, stream>>>(rowptr, packed, B16, A16, emb, out, nN);
        k_pull<2><<<pgrid, blk, 0, stream>>>(rowptr, packed, A16, B16, emb, out, nN);
    } else {
        float* A = (float*)ws;
        float* B = (float*)(ws + hbytes);
        const int n4 = nN * DF / 4;
        const int sgrid = (nE * 8 + 255) / 256;
        const int agrid = (n4 + 255) / 256;
        hipMemsetAsync(B, 0, hbytes, stream);
        spmm_scatter<<<sgrid, blk, 0, stream>>>(src, dst, w, emb, B, nE);
        accum_first<<<agrid, blk, 0, stream>>>(emb, B, out, n4);
        hipMemsetAsync(A, 0, hbytes, stream);
        spmm_scatter<<<sgrid, blk, 0, stream>>>(src, dst, w, B, A, nE);
        accum_mid<<<agrid, blk, 0, stream>>>(A, out, n4);
        hipMemsetAsync(B, 0, hbytes, stream);
        spmm_scatter<<<sgrid, blk, 0, stream>>>(src, dst, w, A, B, nE);
        accum_last<<<agrid, blk, 0, stream>>>(B, out, n4);
    }
}

// Round 9
// 200.501 us; speedup vs baseline: 1.3000x; 1.3000x over previous
//
#include <hip/hip_runtime.h>
#include <stdint.h>

#define DF 32
#define BN 256               // nodes per bucket (dst >> 8)
#define MAXB 512             // max buckets on fast path (nN <= 131072)
#define CHUNK 4096           // edges per partition WG
typedef unsigned long long u64;
typedef unsigned short u16;

static __device__ __forceinline__ u16 f2bf(float x) {     // RTN-even
    unsigned u = __float_as_uint(x);
    return (u16)((u + 0x7fff + ((u >> 16) & 1)) >> 16);
}
static __device__ __forceinline__ float bf2f(u16 b) {
    return __uint_as_float((unsigned)b << 16);
}

__global__ void k_zero(int* __restrict__ p, int n) {
    int i = blockIdx.x * blockDim.x + threadIdx.x;
    if (i < n) p[i] = 0;
}

// ======================= bucket partition prepass =======================

__global__ void k_bcount(const int* __restrict__ dst, int* __restrict__ bcnt,
                         int nE, int nbuck) {
    __shared__ int h[MAXB];
    for (int i = threadIdx.x; i < MAXB; i += blockDim.x) h[i] = 0;
    __syncthreads();
    for (int i = blockIdx.x * blockDim.x + threadIdx.x; i < nE;
         i += gridDim.x * blockDim.x)
        atomicAdd(&h[dst[i] >> 8], 1);
    __syncthreads();
    for (int i = threadIdx.x; i < nbuck; i += blockDim.x)
        if (h[i]) atomicAdd(&bcnt[i], h[i]);
}

__global__ void k_bscan(const int* __restrict__ bcnt, int* __restrict__ bptr,
                        int* __restrict__ bcur, int nbuck) {
    __shared__ int a[MAXB], b[MAXB];
    int t = threadIdx.x;
    int v = (t < nbuck) ? bcnt[t] : 0;
    a[t] = v;
    __syncthreads();
    int* pin = a; int* pout = b;
    for (int off = 1; off < MAXB; off <<= 1) {
        pout[t] = pin[t] + ((t >= off) ? pin[t - off] : 0);
        __syncthreads();
        int* tmp = pin; pin = pout; pout = tmp;
    }
    int inc = pin[t];
    if (t < nbuck) { bptr[t] = inc - v; bcur[t] = inc - v; }
    if (t == nbuck - 1) bptr[nbuck] = inc;
}

// record = w(f32)<<32 | src<<8 | localDst  (needs nN < 2^24)
__global__ __launch_bounds__(512)
void k_bpart(const int* __restrict__ src, const int* __restrict__ dst,
             const float* __restrict__ w, int* __restrict__ bcur,
             u64* __restrict__ rec_g, int nE, int nbuck) {
    __shared__ u64 rec[CHUNK];
    __shared__ unsigned short rb[CHUNK];
    __shared__ int hist[MAXB], sa[MAXB], sb[MAXB], goff[MAXB], cur[MAXB];
    int t = threadIdx.x;
    int base = blockIdx.x * CHUNK;
    int cnt = min(CHUNK, nE - base);

    hist[t] = 0;
    __syncthreads();

    int myb[8]; u64 myrec[8];
#pragma unroll
    for (int j = 0; j < 8; j++) {
        int i = t + j * 512;
        if (i < cnt) {
            int d = dst[base + i];
            myb[j] = d >> 8;
            myrec[j] = ((u64)__float_as_uint(w[base + i]) << 32)
                     | ((u64)(unsigned)src[base + i] << 8)
                     | (u64)(d & (BN - 1));
            atomicAdd(&hist[myb[j]], 1);
        } else myb[j] = -1;
    }
    __syncthreads();

    int v = hist[t];
    sa[t] = v;
    __syncthreads();
    int* pin = sa; int* pout = sb;
    for (int off = 1; off < MAXB; off <<= 1) {
        pout[t] = pin[t] + ((t >= off) ? pin[t - off] : 0);
        __syncthreads();
        int* tmp = pin; pin = pout; pout = tmp;
    }
    int excl = pin[t] - v;
    cur[t] = excl;
    int g = 0;
    if (t < nbuck && v > 0) g = atomicAdd(&bcur[t], v);
    goff[t] = g - excl;
    __syncthreads();

#pragma unroll
    for (int j = 0; j < 8; j++) {
        if (myb[j] >= 0) {
            int p = atomicAdd(&cur[myb[j]], 1);
            rec[p] = myrec[j];
            rb[p] = (unsigned short)myb[j];
        }
    }
    __syncthreads();

    for (int r = t; r < cnt; r += 512) {
        int bb = rb[r];
        rec_g[goff[bb] + r] = rec[r];
    }
}

// one WG per bucket: exact CSR from bucket-sorted rec_g.
// packed = w(f32)<<32 | src  (plain caches — L2 merges the in-window scatter)
__global__ __launch_bounds__(512)
void k_csr(const int* __restrict__ bptr, const u64* __restrict__ rec_g,
           int* __restrict__ rowptr, u64* __restrict__ packed, int nN, int nbuck) {
    __shared__ int cnt[BN], excl[BN];
    int b = blockIdx.x;
    int t = threadIdx.x;
    int s0 = bptr[b], s1 = bptr[b + 1];
    if (t < BN) cnt[t] = 0;
    __syncthreads();
    for (int i = s0 + t; i < s1; i += 512)
        atomicAdd(&cnt[(int)(rec_g[i] & (BN - 1))], 1);
    __syncthreads();
    if (t < BN) excl[t] = cnt[t];
    __syncthreads();
    for (int off = 1; off < BN; off <<= 1) {
        int u = 0;
        if (t < BN && t >= off) u = excl[t - off];
        __syncthreads();
        if (t < BN) excl[t] += u;
        __syncthreads();
    }
    int nodeBase = b * BN;
    if (t < BN) {
        int e = excl[t] - cnt[t];
        if (nodeBase + t < nN) rowptr[nodeBase + t] = s0 + e;
        cnt[t] = e;
    }
    if (b == nbuck - 1 && t == 0) rowptr[nN] = s1;
    __syncthreads();
    for (int i = s0 + t; i < s1; i += 512) {
        u64 r = rec_g[i];
        int ld = (int)(r & (BN - 1));
        int pos = s0 + atomicAdd(&cnt[ld], 1);
        packed[pos] = (r & 0xffffffff00000000ull) | ((r >> 8) & 0xffffffull);
    }
}

// f32 -> bf16 cast (4 elems/thread)
__global__ void k_cast(const float* __restrict__ x, u16* __restrict__ y, int n4) {
    int i = blockIdx.x * blockDim.x + threadIdx.x;
    if (i >= n4) return;
    float4 v = reinterpret_cast<const float4*>(x)[i];
    ushort4 o;
    o.x = f2bf(v.x); o.y = f2bf(v.y); o.z = f2bf(v.z); o.w = f2bf(v.w);
    reinterpret_cast<ushort4*>(y)[i] = o;
}

// ======================= pull SpMM (bf16 gathers, pipelined unroll-4) ========
// half-wave per node: lane f owns feature f. 1024-thread blocks (32 nodes/WG)
// cut WG churn; packed loads for batch b+1 are prefetched while batch b's
// gathers are in flight (removes packed latency from the serial chain).
// MODE: 0 first (out = emb+acc, hn=bf16(acc)), 1 mid (out+=acc, hn=bf16(acc)),
// 2 last (out = (out+acc)*0.25)
template <int MODE>
__global__ __launch_bounds__(1024)
void k_pull(const int* __restrict__ rowptr, const u64* __restrict__ packed,
            const u16* __restrict__ h16, u16* __restrict__ hn16,
            const float* __restrict__ emb, float* __restrict__ out, int n) {
    int gid = blockIdx.x * blockDim.x + threadIdx.x;
    int node = gid >> 5;
    int f = gid & 31;
    if (node >= n) return;
    int s0 = rowptr[node], s1 = rowptr[node + 1];
    float acc0 = 0.f, acc1 = 0.f, acc2 = 0.f, acc3 = 0.f;
    int nb = (s1 - s0) >> 2;                      // full 4-edge batches
    int i = s0;
    if (nb > 0) {
        u64 q0 = packed[i], q1 = packed[i + 1], q2 = packed[i + 2], q3 = packed[i + 3];
        for (int b = 1; b < nb; b++) {
            int j = s0 + b * 4;
            u64 r0 = packed[j], r1 = packed[j + 1],          // prefetch next
                r2 = packed[j + 2], r3 = packed[j + 3];
            float v0 = bf2f(h16[(size_t)(unsigned)(q0 & 0xffffffffu) * DF + f]);
            float v1 = bf2f(h16[(size_t)(unsigned)(q1 & 0xffffffffu) * DF + f]);
            float v2 = bf2f(h16[(size_t)(unsigned)(q2 & 0xffffffffu) * DF + f]);
            float v3 = bf2f(h16[(size_t)(unsigned)(q3 & 0xffffffffu) * DF + f]);
            acc0 += __uint_as_float((unsigned)(q0 >> 32)) * v0;
            acc1 += __uint_as_float((unsigned)(q1 >> 32)) * v1;
            acc2 += __uint_as_float((unsigned)(q2 >> 32)) * v2;
            acc3 += __uint_as_float((unsigned)(q3 >> 32)) * v3;
            q0 = r0; q1 = r1; q2 = r2; q3 = r3;
        }
        float v0 = bf2f(h16[(size_t)(unsigned)(q0 & 0xffffffffu) * DF + f]);
        float v1 = bf2f(h16[(size_t)(unsigned)(q1 & 0xffffffffu) * DF + f]);
        float v2 = bf2f(h16[(size_t)(unsigned)(q2 & 0xffffffffu) * DF + f]);
        float v3 = bf2f(h16[(size_t)(unsigned)(q3 & 0xffffffffu) * DF + f]);
        acc0 += __uint_as_float((unsigned)(q0 >> 32)) * v0;
        acc1 += __uint_as_float((unsigned)(q1 >> 32)) * v1;
        acc2 += __uint_as_float((unsigned)(q2 >> 32)) * v2;
        acc3 += __uint_as_float((unsigned)(q3 >> 32)) * v3;
        i = s0 + nb * 4;
    }
    for (; i < s1; i++) {
        u64 p = packed[i];
        acc0 += __uint_as_float((unsigned)(p >> 32))
              * bf2f(h16[(size_t)(unsigned)(p & 0xffffffffu) * DF + f]);
    }
    float acc = (acc0 + acc1) + (acc2 + acc3);
    size_t o = (size_t)node * DF + f;
    if (MODE == 0)      { hn16[o] = f2bf(acc); out[o] = emb[o] + acc; }
    else if (MODE == 1) { hn16[o] = f2bf(acc); out[o] += acc; }
    else                { out[o] = (out[o] + acc) * 0.25f; }
}

// ======================= fallback (R1 atomic path, f32) =======================

__global__ void spmm_scatter(const int* __restrict__ src, const int* __restrict__ dst,
                             const float* __restrict__ w, const float* __restrict__ h,
                             float* __restrict__ hn, int nE) {
    int i = blockIdx.x * blockDim.x + threadIdx.x;
    int total = nE * 8;
    if (i >= total) return;
    int e = i >> 3, g = i & 7;
    int s = src[e], t = dst[e];
    float wt = w[e];
    float4 v = reinterpret_cast<const float4*>(h)[(size_t)s * 8 + g];
    float* p = hn + (size_t)t * DF + g * 4;
    atomicAdd(p + 0, v.x * wt); atomicAdd(p + 1, v.y * wt);
    atomicAdd(p + 2, v.z * wt); atomicAdd(p + 3, v.w * wt);
}
__global__ void accum_first(const float* __restrict__ emb, const float* __restrict__ hn,
                            float* __restrict__ out, int n4) {
    int i = blockIdx.x * blockDim.x + threadIdx.x;
    if (i >= n4) return;
    float4 a = reinterpret_cast<const float4*>(emb)[i];
    float4 b = reinterpret_cast<const float4*>(hn)[i];
    reinterpret_cast<float4*>(out)[i] = make_float4(a.x+b.x, a.y+b.y, a.z+b.z, a.w+b.w);
}
__global__ void accum_mid(const float* __restrict__ hn, float* __restrict__ out, int n4) {
    int i = blockIdx.x * blockDim.x + threadIdx.x;
    if (i >= n4) return;
    float4 a = reinterpret_cast<float4*>(out)[i];
    float4 b = reinterpret_cast<const float4*>(hn)[i];
    reinterpret_cast<float4*>(out)[i] = make_float4(a.x+b.x, a.y+b.y, a.z+b.z, a.w+b.w);
}
__global__ void accum_last(const float* __restrict__ hn, float* __restrict__ out, int n4) {
    int i = blockIdx.x * blockDim.x + threadIdx.x;
    if (i >= n4) return;
    float4 a = reinterpret_cast<float4*>(out)[i];
    float4 b = reinterpret_cast<const float4*>(hn)[i];
    reinterpret_cast<float4*>(out)[i] = make_float4((a.x+b.x)*0.25f, (a.y+b.y)*0.25f,
                                                    (a.z+b.z)*0.25f, (a.w+b.w)*0.25f);
}

// ======================= launch =======================

extern "C" void kernel_launch(void* const* d_in, const int* in_sizes, int n_in,
                              void* d_out, int out_size, void* d_ws, size_t ws_size,
                              hipStream_t stream) {
    const float* emb = (const float*)d_in[0];
    const int*   src = (const int*)d_in[1];
    const int*   dst = (const int*)d_in[2];
    const float* w   = (const float*)d_in[3];
    float* out = (float*)d_out;

    const int nN = in_sizes[0] / DF;
    const int nE = in_sizes[1];
    const int nbuck = (nN + BN - 1) / BN;
    const size_t hbytes  = (size_t)nN * DF * sizeof(float);   // f32 matrix
    const size_t h16b    = (size_t)nN * DF * 2;               // bf16 matrix

    char* ws = (char*)d_ws;
    u16* E16 = (u16*)ws;
    u16* B16 = (u16*)(ws + h16b);
    u16* A16 = (u16*)(ws + 2 * h16b);
    u64* rec_g = (u64*)(ws + h16b);          // overlaps B16/A16; dead before pulls
    size_t recb = (((size_t)nE * 8 + 63) / 64) * 64;
    size_t off_pk = h16b + (recb > 2 * h16b ? recb : 2 * h16b);
    u64* packed = (u64*)(ws + off_pk);
    size_t roff = off_pk + recb;
    int* rowptr = (int*)(ws + roff);
    size_t boff = roff + (((size_t)(nN + 1) * 4 + 63) / 64) * 64;
    int* bcnt = (int*)(ws + boff);
    int* bptr = bcnt + MAXB;
    int* bcur = bptr + MAXB + 1;
    const size_t need = boff + (size_t)(3 * MAXB + 1) * 4;

    const dim3 blk(256);

    if (nbuck <= MAXB && nN < (1 << 24) && ws_size >= need) {
        const int n4 = nN * DF / 4;
        k_zero<<<(MAXB + 255) / 256, blk, 0, stream>>>(bcnt, MAXB);
        k_cast<<<(n4 + 255) / 256, blk, 0, stream>>>(emb, E16, n4);
        k_bcount<<<512, blk, 0, stream>>>(dst, bcnt, nE, nbuck);
        k_bscan<<<1, MAXB, 0, stream>>>(bcnt, bptr, bcur, nbuck);
        k_bpart<<<(nE + CHUNK - 1) / CHUNK, 512, 0, stream>>>(src, dst, w, bcur,
                                                              rec_g, nE, nbuck);
        k_csr<<<nbuck, 512, 0, stream>>>(bptr, rec_g, rowptr, packed, nN, nbuck);

        const int pgrid = (nN * 32 + 1023) / 1024;
        k_pull<0><<<pgrid, 1024, 0, stream>>>(rowptr, packed, E16, B16, emb, out, nN);
        k_pull<1><<<pgrid, 1024, 0, stream>>>(rowptr, packed, B16, A16, emb, out, nN);
        k_pull<2><<<pgrid, 1024, 0, stream>>>(rowptr, packed, A16, B16, emb, out, nN);
    } else {
        float* A = (float*)ws;
        float* B = (float*)(ws + hbytes);
        const int n4 = nN * DF / 4;
        const int sgrid = (nE * 8 + 255) / 256;
        const int agrid = (n4 + 255) / 256;
        hipMemsetAsync(B, 0, hbytes, stream);
        spmm_scatter<<<sgrid, blk, 0, stream>>>(src, dst, w, emb, B, nE);
        accum_first<<<agrid, blk, 0, stream>>>(emb, B, out, n4);
        hipMemsetAsync(A, 0, hbytes, stream);
        spmm_scatter<<<sgrid, blk, 0, stream>>>(src, dst, w, B, A, nE);
        accum_mid<<<agrid, blk, 0, stream>>>(A, out, n4);
        hipMemsetAsync(B, 0, hbytes, stream);
        spmm_scatter<<<sgrid, blk, 0, stream>>>(src, dst, w, A, B, nE);
        accum_last<<<agrid, blk, 0, stream>>>(B, out, n4);
    }
}

// Round 10
// 151.277 us; speedup vs baseline: 1.7229x; 1.3254x over previous
//
#include <hip/hip_runtime.h>
#include <stdint.h>

#define DF 32
#define BN 256               // nodes per bucket (dst >> 8)
#define MAXB 512             // max buckets on fast path (nN <= 131072)
#define CHUNK 4096           // edges per partition WG
typedef unsigned long long u64;
typedef unsigned short u16;
typedef unsigned int u32;

static __device__ __forceinline__ u16 f2bf(float x) {     // RTN-even
    unsigned u = __float_as_uint(x);
    return (u16)((u + 0x7fff + ((u >> 16) & 1)) >> 16);
}
static __device__ __forceinline__ float bf2f(u16 b) {
    return __uint_as_float((unsigned)b << 16);
}

__global__ void k_zero(int* __restrict__ p, int n) {
    int i = blockIdx.x * blockDim.x + threadIdx.x;
    if (i < n) p[i] = 0;
}

// ======================= bucket partition prepass =======================

__global__ void k_bcount(const int* __restrict__ dst, int* __restrict__ bcnt,
                         int nE, int nbuck) {
    __shared__ int h[MAXB];
    for (int i = threadIdx.x; i < MAXB; i += blockDim.x) h[i] = 0;
    __syncthreads();
    for (int i = blockIdx.x * blockDim.x + threadIdx.x; i < nE;
         i += gridDim.x * blockDim.x)
        atomicAdd(&h[dst[i] >> 8], 1);
    __syncthreads();
    for (int i = threadIdx.x; i < nbuck; i += blockDim.x)
        if (h[i]) atomicAdd(&bcnt[i], h[i]);
}

__global__ void k_bscan(const int* __restrict__ bcnt, int* __restrict__ bptr,
                        int* __restrict__ bcur, int nbuck) {
    __shared__ int a[MAXB], b[MAXB];
    int t = threadIdx.x;
    int v = (t < nbuck) ? bcnt[t] : 0;
    a[t] = v;
    __syncthreads();
    int* pin = a; int* pout = b;
    for (int off = 1; off < MAXB; off <<= 1) {
        pout[t] = pin[t] + ((t >= off) ? pin[t - off] : 0);
        __syncthreads();
        int* tmp = pin; pin = pout; pout = tmp;
    }
    int inc = pin[t];
    if (t < nbuck) { bptr[t] = inc - v; bcur[t] = inc - v; }
    if (t == nbuck - 1) bptr[nbuck] = inc;
}

// record = wbits15<<25 | src<<8 | localDst  (src needs <= 17 bits)
__global__ __launch_bounds__(512)
void k_bpart(const int* __restrict__ src, const int* __restrict__ dst,
             const float* __restrict__ w, int* __restrict__ bcur,
             u64* __restrict__ rec_g, int nE, int nbuck) {
    __shared__ u64 rec[CHUNK];
    __shared__ unsigned short rb[CHUNK];
    __shared__ int hist[MAXB], sa[MAXB], sb[MAXB], goff[MAXB], cur[MAXB];
    int t = threadIdx.x;
    int base = blockIdx.x * CHUNK;
    int cnt = min(CHUNK, nE - base);

    hist[t] = 0;
    __syncthreads();

    int myb[8]; u64 myrec[8];
#pragma unroll
    for (int j = 0; j < 8; j++) {
        int i = t + j * 512;
        if (i < cnt) {
            int d = dst[base + i];
            myb[j] = d >> 8;
            u32 wbits = f2bf(w[base + i]) & 0x7fffu;   // w>=0: drop sign, bf16
            myrec[j] = ((u64)wbits << 25)
                     | ((u64)(unsigned)src[base + i] << 8)
                     | (u64)(d & (BN - 1));
            atomicAdd(&hist[myb[j]], 1);
        } else myb[j] = -1;
    }
    __syncthreads();

    int v = hist[t];
    sa[t] = v;
    __syncthreads();
    int* pin = sa; int* pout = sb;
    for (int off = 1; off < MAXB; off <<= 1) {
        pout[t] = pin[t] + ((t >= off) ? pin[t - off] : 0);
        __syncthreads();
        int* tmp = pin; pin = pout; pout = tmp;
    }
    int excl = pin[t] - v;
    cur[t] = excl;
    int g = 0;
    if (t < nbuck && v > 0) g = atomicAdd(&bcur[t], v);
    goff[t] = g - excl;
    __syncthreads();

#pragma unroll
    for (int j = 0; j < 8; j++) {
        if (myb[j] >= 0) {
            int p = atomicAdd(&cur[myb[j]], 1);
            rec[p] = myrec[j];
            rb[p] = (unsigned short)myb[j];
        }
    }
    __syncthreads();

    for (int r = t; r < cnt; r += 512) {
        int bb = rb[r];
        rec_g[goff[bb] + r] = rec[r];
    }
}

// one WG per bucket: exact CSR from bucket-sorted rec_g.
// packed(u32) = wbits15<<17 | src
__global__ __launch_bounds__(512)
void k_csr(const int* __restrict__ bptr, const u64* __restrict__ rec_g,
           int* __restrict__ rowptr, u32* __restrict__ packed, int nN, int nbuck) {
    __shared__ int cnt[BN], excl[BN];
    int b = blockIdx.x;
    int t = threadIdx.x;
    int s0 = bptr[b], s1 = bptr[b + 1];
    if (t < BN) cnt[t] = 0;
    __syncthreads();
    for (int i = s0 + t; i < s1; i += 512)
        atomicAdd(&cnt[(int)(rec_g[i] & (BN - 1))], 1);
    __syncthreads();
    if (t < BN) excl[t] = cnt[t];
    __syncthreads();
    for (int off = 1; off < BN; off <<= 1) {
        int u = 0;
        if (t < BN && t >= off) u = excl[t - off];
        __syncthreads();
        if (t < BN) excl[t] += u;
        __syncthreads();
    }
    int nodeBase = b * BN;
    if (t < BN) {
        int e = excl[t] - cnt[t];
        if (nodeBase + t < nN) rowptr[nodeBase + t] = s0 + e;
        cnt[t] = e;
    }
    if (b == nbuck - 1 && t == 0) rowptr[nN] = s1;
    __syncthreads();
    for (int i = s0 + t; i < s1; i += 512) {
        u64 r = rec_g[i];
        int ld = (int)(r & (BN - 1));
        int pos = s0 + atomicAdd(&cnt[ld], 1);
        packed[pos] = (u32)(((r >> 25) & 0x7fffull) << 17) | (u32)((r >> 8) & 0x1ffffull);
    }
}

// f32 -> bf16 cast (4 elems/thread)
__global__ void k_cast(const float* __restrict__ x, u16* __restrict__ y, int n4) {
    int i = blockIdx.x * blockDim.x + threadIdx.x;
    if (i >= n4) return;
    float4 v = reinterpret_cast<const float4*>(x)[i];
    ushort4 o;
    o.x = f2bf(v.x); o.y = f2bf(v.y); o.z = f2bf(v.z); o.w = f2bf(v.w);
    reinterpret_cast<ushort4*>(y)[i] = o;
}

// ======================= pull SpMM (16-lane groups, 2 feat/lane) =============
// 16 lanes per node; lane g owns features {2g, 2g+1} as one u32 (2xbf16).
// h viewed as u32[nN][16]. packed is u32: wbits15<<17 | src.
// MODE: 0 first (out = bf2f(E16)+acc), 1 mid (out += acc), 2 last
// (out = (out+acc)*0.25, no hn write)
template <int MODE>
__global__ void k_pull(const int* __restrict__ rowptr, const u32* __restrict__ packed,
                       const u32* __restrict__ h32, u32* __restrict__ hn32,
                       const u32* __restrict__ e32, float* __restrict__ out, int n) {
    int gid = blockIdx.x * blockDim.x + threadIdx.x;
    int node = gid >> 4;
    int g = gid & 15;
    if (node >= n) return;
    int s0 = rowptr[node], s1 = rowptr[node + 1];
    float al0 = 0.f, ah0 = 0.f, al1 = 0.f, ah1 = 0.f,
          al2 = 0.f, ah2 = 0.f, al3 = 0.f, ah3 = 0.f;
    int i = s0;
    for (; i + 4 <= s1; i += 4) {                 // 4 gathers in flight
        u32 p0 = packed[i], p1 = packed[i + 1], p2 = packed[i + 2], p3 = packed[i + 3];
        u32 v0 = h32[(size_t)(p0 & 0x1ffffu) * 16 + g];
        u32 v1 = h32[(size_t)(p1 & 0x1ffffu) * 16 + g];
        u32 v2 = h32[(size_t)(p2 & 0x1ffffu) * 16 + g];
        u32 v3 = h32[(size_t)(p3 & 0x1ffffu) * 16 + g];
        float w0 = __uint_as_float((p0 >> 17) << 16);
        float w1 = __uint_as_float((p1 >> 17) << 16);
        float w2 = __uint_as_float((p2 >> 17) << 16);
        float w3 = __uint_as_float((p3 >> 17) << 16);
        al0 += w0 * bf2f((u16)(v0 & 0xffff)); ah0 += w0 * bf2f((u16)(v0 >> 16));
        al1 += w1 * bf2f((u16)(v1 & 0xffff)); ah1 += w1 * bf2f((u16)(v1 >> 16));
        al2 += w2 * bf2f((u16)(v2 & 0xffff)); ah2 += w2 * bf2f((u16)(v2 >> 16));
        al3 += w3 * bf2f((u16)(v3 & 0xffff)); ah3 += w3 * bf2f((u16)(v3 >> 16));
    }
    for (; i < s1; i++) {
        u32 p = packed[i];
        u32 v = h32[(size_t)(p & 0x1ffffu) * 16 + g];
        float wt = __uint_as_float((p >> 17) << 16);
        al0 += wt * bf2f((u16)(v & 0xffff));
        ah0 += wt * bf2f((u16)(v >> 16));
    }
    float accL = (al0 + al1) + (al2 + al3);
    float accH = (ah0 + ah1) + (ah2 + ah3);
    size_t o32 = (size_t)node * 16 + g;
    if (MODE != 2) {
        hn32[o32] = (u32)f2bf(accL) | ((u32)f2bf(accH) << 16);
    }
    float2* outp = reinterpret_cast<float2*>(out) + o32;
    if (MODE == 0) {
        u32 e = e32[o32];
        float2 r;
        r.x = bf2f((u16)(e & 0xffff)) + accL;
        r.y = bf2f((u16)(e >> 16)) + accH;
        *outp = r;
    } else if (MODE == 1) {
        float2 ov = *outp;
        ov.x += accL; ov.y += accH;
        *outp = ov;
    } else {
        float2 ov = *outp;
        ov.x = (ov.x + accL) * 0.25f; ov.y = (ov.y + accH) * 0.25f;
        *outp = ov;
    }
}

// ======================= fallback (R1 atomic path, f32) =======================

__global__ void spmm_scatter(const int* __restrict__ src, const int* __restrict__ dst,
                             const float* __restrict__ w, const float* __restrict__ h,
                             float* __restrict__ hn, int nE) {
    int i = blockIdx.x * blockDim.x + threadIdx.x;
    int total = nE * 8;
    if (i >= total) return;
    int e = i >> 3, g = i & 7;
    int s = src[e], t = dst[e];
    float wt = w[e];
    float4 v = reinterpret_cast<const float4*>(h)[(size_t)s * 8 + g];
    float* p = hn + (size_t)t * DF + g * 4;
    atomicAdd(p + 0, v.x * wt); atomicAdd(p + 1, v.y * wt);
    atomicAdd(p + 2, v.z * wt); atomicAdd(p + 3, v.w * wt);
}
__global__ void accum_first(const float* __restrict__ emb, const float* __restrict__ hn,
                            float* __restrict__ out, int n4) {
    int i = blockIdx.x * blockDim.x + threadIdx.x;
    if (i >= n4) return;
    float4 a = reinterpret_cast<const float4*>(emb)[i];
    float4 b = reinterpret_cast<const float4*>(hn)[i];
    reinterpret_cast<float4*>(out)[i] = make_float4(a.x+b.x, a.y+b.y, a.z+b.z, a.w+b.w);
}
__global__ void accum_mid(const float* __restrict__ hn, float* __restrict__ out, int n4) {
    int i = blockIdx.x * blockDim.x + threadIdx.x;
    if (i >= n4) return;
    float4 a = reinterpret_cast<float4*>(out)[i];
    float4 b = reinterpret_cast<const float4*>(hn)[i];
    reinterpret_cast<float4*>(out)[i] = make_float4(a.x+b.x, a.y+b.y, a.z+b.z, a.w+b.w);
}
__global__ void accum_last(const float* __restrict__ hn, float* __restrict__ out, int n4) {
    int i = blockIdx.x * blockDim.x + threadIdx.x;
    if (i >= n4) return;
    float4 a = reinterpret_cast<float4*>(out)[i];
    float4 b = reinterpret_cast<const float4*>(hn)[i];
    reinterpret_cast<float4*>(out)[i] = make_float4((a.x+b.x)*0.25f, (a.y+b.y)*0.25f,
                                                    (a.z+b.z)*0.25f, (a.w+b.w)*0.25f);
}

// ======================= launch =======================

extern "C" void kernel_launch(void* const* d_in, const int* in_sizes, int n_in,
                              void* d_out, int out_size, void* d_ws, size_t ws_size,
                              hipStream_t stream) {
    const float* emb = (const float*)d_in[0];
    const int*   src = (const int*)d_in[1];
    const int*   dst = (const int*)d_in[2];
    const float* w   = (const float*)d_in[3];
    float* out = (float*)d_out;

    const int nN = in_sizes[0] / DF;
    const int nE = in_sizes[1];
    const int nbuck = (nN + BN - 1) / BN;
    const size_t hbytes  = (size_t)nN * DF * sizeof(float);   // f32 matrix
    const size_t h16b    = (size_t)nN * DF * 2;               // bf16 matrix

    char* ws = (char*)d_ws;
    u16* E16 = (u16*)ws;
    u16* B16 = (u16*)(ws + h16b);
    u16* A16 = (u16*)(ws + 2 * h16b);
    u64* rec_g = (u64*)(ws + h16b);          // overlaps B16/A16; dead before pulls
    size_t recb = (((size_t)nE * 8 + 63) / 64) * 64;
    size_t off_pk = h16b + (recb > 2 * h16b ? recb : 2 * h16b);
    u32* packed = (u32*)(ws + off_pk);
    size_t roff = off_pk + (((size_t)nE * 4 + 63) / 64) * 64;
    int* rowptr = (int*)(ws + roff);
    size_t boff = roff + (((size_t)(nN + 1) * 4 + 63) / 64) * 64;
    int* bcnt = (int*)(ws + boff);
    int* bptr = bcnt + MAXB;
    int* bcur = bptr + MAXB + 1;
    const size_t need = boff + (size_t)(3 * MAXB + 1) * 4;

    const dim3 blk(256);

    if (nbuck <= MAXB && nN <= (1 << 17) && ws_size >= need) {
        const int n4 = nN * DF / 4;
        k_zero<<<(MAXB + 255) / 256, blk, 0, stream>>>(bcnt, MAXB);
        k_cast<<<(n4 + 255) / 256, blk, 0, stream>>>(emb, E16, n4);
        k_bcount<<<512, blk, 0, stream>>>(dst, bcnt, nE, nbuck);
        k_bscan<<<1, MAXB, 0, stream>>>(bcnt, bptr, bcur, nbuck);
        k_bpart<<<(nE + CHUNK - 1) / CHUNK, 512, 0, stream>>>(src, dst, w, bcur,
                                                              rec_g, nE, nbuck);
        k_csr<<<nbuck, 512, 0, stream>>>(bptr, rec_g, rowptr, packed, nN, nbuck);

        const int pgrid = (nN * 16 + 255) / 256;
        k_pull<0><<<pgrid, blk, 0, stream>>>(rowptr, packed, (u32*)E16, (u32*)B16,
                                             (u32*)E16, out, nN);
        k_pull<1><<<pgrid, blk, 0, stream>>>(rowptr, packed, (u32*)B16, (u32*)A16,
                                             (u32*)E16, out, nN);
        k_pull<2><<<pgrid, blk, 0, stream>>>(rowptr, packed, (u32*)A16, (u32*)B16,
                                             (u32*)E16, out, nN);
    } else {
        float* A = (float*)ws;
        float* B = (float*)(ws + hbytes);
        const int n4 = nN * DF / 4;
        const int sgrid = (nE * 8 + 255) / 256;
        const int agrid = (n4 + 255) / 256;
        hipMemsetAsync(B, 0, hbytes, stream);
        spmm_scatter<<<sgrid, blk, 0, stream>>>(src, dst, w, emb, B, nE);
        accum_first<<<agrid, blk, 0, stream>>>(emb, B, out, n4);
        hipMemsetAsync(A, 0, hbytes, stream);
        spmm_scatter<<<sgrid, blk, 0, stream>>>(src, dst, w, B, A, nE);
        accum_mid<<<agrid, blk, 0, stream>>>(A, out, n4);
        hipMemsetAsync(B, 0, hbytes, stream);
        spmm_scatter<<<sgrid, blk, 0, stream>>>(src, dst, w, A, B, nE);
        accum_last<<<agrid, blk, 0, stream>>>(B, out, n4);
    }
}